// Round 1
// baseline (196.370 us; speedup 1.0000x reference)
//
#include <hip/hip_runtime.h>

#define UNITS 512
#define SENSD 256
#define BATCH 256
#define BN (BATCH * UNITS)
#define LOG2E 1.44269504088896340736f
#define CMF (6.0f / 1.001f)   // ODE_UNFOLDS / (ELAPSED_TIME + 0.001)

__device__ __forceinline__ float frcp(float x)  { return __builtin_amdgcn_rcpf(x); }
__device__ __forceinline__ float fexp2(float x) { return __builtin_amdgcn_exp2f(x); }

// Fused params: fusedR/fusedS[pq] = {-sigma*log2e, sigma*mu*log2e, w, w*erev}
// cmg[p] = {cm_t, gleak*vleak, cm_t+gleak+eps, 0}
__global__ __launch_bounds__(256) void prep_kernel(
    const float* __restrict__ sigma, const float* __restrict__ mu,
    const float* __restrict__ w, const float* __restrict__ erev,
    const float* __restrict__ ssig, const float* __restrict__ smu,
    const float* __restrict__ sw, const float* __restrict__ serev,
    const float* __restrict__ gleak, const float* __restrict__ vleak,
    const float* __restrict__ cm,
    float4* __restrict__ fusedR, float4* __restrict__ fusedS,
    float4* __restrict__ cmg) {
  int idx = blockIdx.x * 256 + threadIdx.x;
  if (idx < UNITS * UNITS) {
    float s = sigma[idx], m = mu[idx], ww = w[idx], e = erev[idx];
    fusedR[idx] = make_float4(-s * LOG2E, s * m * LOG2E, ww, ww * e);
  } else {
    int j = idx - UNITS * UNITS;
    if (j < SENSD * UNITS) {
      float s = ssig[j], m = smu[j], ww = sw[j], e = serev[j];
      fusedS[j] = make_float4(-s * LOG2E, s * m * LOG2E, ww, ww * e);
    }
  }
  if (idx < UNITS) {
    float cmt = cm[idx] * CMF, gl = gleak[idx];
    cmg[idx] = make_float4(cmt, gl * vleak[idx], cmt + gl + 1e-8f, 0.f);
  }
}

// Sensory partials over 2 d-chunks of 128, 4 batch rows per thread.
// grid 256: bi = phs + 2*(qt + 8*bt); phs<2, qt<8 (q64), bt<16 (btile 16)
// 256 thr = 64 q-lanes x 4 bgroups; each thread handles rows r0..r0+3.
// Outputs plane layout snf/sdf[2][BN].
__global__ __launch_bounds__(256, 2) void sensory_kernel(
    const float* __restrict__ x, const float* __restrict__ in_w, const float* __restrict__ in_b,
    const float4* __restrict__ fusedS,
    float* __restrict__ snf, float* __restrict__ sdf) {
  __shared__ float xl[128][20];   // [d-lane][batch-row], pad 20 -> 16B-aligned rows of 4
  int bi = blockIdx.x;
  int phs = bi & 1, qt = (bi >> 1) & 7, bt = bi >> 4;
  int tid = threadIdx.x;
  for (int i = tid; i < 2048; i += 256) {
    int br = i >> 7, dl = i & 127;
    int d = phs * 128 + dl;
    xl[dl][br] = fmaf(x[(bt * 16 + br) * SENSD + d], in_w[d], in_b[d]);
  }
  __syncthreads();
  int ql = tid & 63, bg = tid >> 6;   // bg < 4
  int q = qt * 64 + ql;
  int r0 = bg * 4;
  const float4* F = fusedS + (size_t)(phs * 128) * UNITS + q;
  float n0 = 0.f, n1 = 0.f, n2 = 0.f, n3 = 0.f;
  float d0 = 0.f, d1 = 0.f, d2 = 0.f, d3 = 0.f;
  #pragma unroll 8
  for (int dd = 0; dd < 128; ++dd) {
    float4 f = F[(size_t)dd * UNITS];
    float4 vv = *(const float4*)&xl[dd][r0];   // broadcast ds_read_b128
    float t0 = fexp2(fmaf(f.x, vv.x, f.y));
    float t1 = fexp2(fmaf(f.x, vv.y, f.y));
    float t2 = fexp2(fmaf(f.x, vv.z, f.y));
    float t3 = fexp2(fmaf(f.x, vv.w, f.y));
    float s0 = frcp(1.0f + t0);
    float s1 = frcp(1.0f + t1);
    float s2 = frcp(1.0f + t2);
    float s3 = frcp(1.0f + t3);
    n0 = fmaf(f.w, s0, n0);  d0 = fmaf(f.z, s0, d0);
    n1 = fmaf(f.w, s1, n1);  d1 = fmaf(f.z, s1, d1);
    n2 = fmaf(f.w, s2, n2);  d2 = fmaf(f.z, s2, d2);
    n3 = fmaf(f.w, s3, n3);  d3 = fmaf(f.z, s3, d3);
  }
  int bp = (bt * 16 + r0) * UNITS + q;
  size_t o = (size_t)phs * BN + bp;
  snf[o] = n0;             sdf[o] = d0;
  snf[o + UNITS] = n1;     sdf[o + UNITS] = d1;
  snf[o + 2 * UNITS] = n2; sdf[o + 2 * UNITS] = d2;
  snf[o + 3 * UNITS] = n3; sdf[o + 3 * UNITS] = d3;
}

// One ODE unfold, 4 batch rows per thread.
// grid 512 x 256 thr: bi = ph + 4*(qt + 8*bt); ph<4 (p-chunk 128), qt<8 (q64),
// bt<16 (btile 16). Prologue reconstructs v_k for this (ph,bt) tile from plane
// partials; qt==0 blocks persist it to vout. Partials out in plane layout [4][BN].
__global__ __launch_bounds__(256, 2) void unfold_kernel(
    const float4* __restrict__ fusedR, const float* __restrict__ vprev,
    const float* __restrict__ pn_in, const float* __restrict__ pd_in,  // [4][BN]
    const float* __restrict__ snf, const float* __restrict__ sdf,      // [2][BN]
    const float4* __restrict__ cmg,
    float* __restrict__ vout,
    float* __restrict__ pn_out, float* __restrict__ pd_out,            // [4][BN]
    int first) {
  __shared__ float vl[128][20];   // [p-lane][batch-row], padded
  int bi = blockIdx.x;
  int ph = bi & 3, qt = (bi >> 2) & 7, bt = bi >> 5;
  int tid = threadIdx.x;
  if (first) {
    for (int i = tid; i < 2048; i += 256) {
      int br = i >> 7, pl = i & 127;
      vl[pl][br] = vprev[(bt * 16 + br) * UNITS + ph * 128 + pl];
    }
  } else {
    for (int i = tid; i < 2048; i += 256) {
      int br = i >> 7, pl = i & 127;
      int p = ph * 128 + pl;
      int bp = (bt * 16 + br) * UNITS + p;
      float num = ((pn_in[bp] + pn_in[BN + bp]) + (pn_in[2 * BN + bp] + pn_in[3 * BN + bp]))
                + (snf[bp] + snf[BN + bp]);
      float den = ((pd_in[bp] + pd_in[BN + bp]) + (pd_in[2 * BN + bp] + pd_in[3 * BN + bp]))
                + (sdf[bp] + sdf[BN + bp]);
      float4 c = cmg[p];
      float v = fmaf(c.x, vprev[bp], c.y + num) * frcp(c.z + den);
      vl[pl][br] = v;
      if (qt == 0) vout[bp] = v;
    }
  }
  __syncthreads();
  int ql = tid & 63, bg = tid >> 6;   // bg < 4
  int q = qt * 64 + ql;
  int r0 = bg * 4;
  const float4* F = fusedR + (size_t)(ph * 128) * UNITS + q;
  float n0 = 0.f, n1 = 0.f, n2 = 0.f, n3 = 0.f;
  float d0 = 0.f, d1 = 0.f, d2 = 0.f, d3 = 0.f;
  #pragma unroll 8
  for (int pp = 0; pp < 128; ++pp) {
    float4 f = F[(size_t)pp * UNITS];
    float4 vv = *(const float4*)&vl[pp][r0];   // broadcast ds_read_b128
    float t0 = fexp2(fmaf(f.x, vv.x, f.y));
    float t1 = fexp2(fmaf(f.x, vv.y, f.y));
    float t2 = fexp2(fmaf(f.x, vv.z, f.y));
    float t3 = fexp2(fmaf(f.x, vv.w, f.y));
    float s0 = frcp(1.0f + t0);
    float s1 = frcp(1.0f + t1);
    float s2 = frcp(1.0f + t2);
    float s3 = frcp(1.0f + t3);
    n0 = fmaf(f.w, s0, n0);  d0 = fmaf(f.z, s0, d0);
    n1 = fmaf(f.w, s1, n1);  d1 = fmaf(f.z, s1, d1);
    n2 = fmaf(f.w, s2, n2);  d2 = fmaf(f.z, s2, d2);
    n3 = fmaf(f.w, s3, n3);  d3 = fmaf(f.z, s3, d3);
  }
  int bp = (bt * 16 + r0) * UNITS + q;
  size_t o = (size_t)ph * BN + bp;
  pn_out[o] = n0;             pd_out[o] = d0;
  pn_out[o + UNITS] = n1;     pd_out[o + UNITS] = d1;
  pn_out[o + 2 * UNITS] = n2; pd_out[o + 2 * UNITS] = d2;
  pn_out[o + 3 * UNITS] = n3; pd_out[o + 3 * UNITS] = d3;
}

// Final combine: v6 from partials_5; write outputs and v_pre.
__global__ __launch_bounds__(256) void final_kernel(
    const float* __restrict__ vprev,
    const float* __restrict__ pn, const float* __restrict__ pd,   // [4][BN]
    const float* __restrict__ snf, const float* __restrict__ sdf, // [2][BN]
    const float4* __restrict__ cmg,
    const float* __restrict__ ow, const float* __restrict__ ob,
    float* __restrict__ out) {
  int idx = blockIdx.x * 256 + threadIdx.x;
  if (idx >= BN) return;
  int p = idx & (UNITS - 1);
  float num = ((pn[idx] + pn[BN + idx]) + (pn[2 * BN + idx] + pn[3 * BN + idx]))
            + (snf[idx] + snf[BN + idx]);
  float den = ((pd[idx] + pd[BN + idx]) + (pd[2 * BN + idx] + pd[3 * BN + idx]))
            + (sdf[idx] + sdf[BN + idx]);
  float4 c = cmg[p];
  float v = fmaf(c.x, vprev[idx], c.y + num) * frcp(c.z + den);
  out[idx] = fmaf(v, ow[p], ob[p]);
  out[BN + idx] = v;
}

extern "C" void kernel_launch(void* const* d_in, const int* in_sizes, int n_in,
                              void* d_out, int out_size, void* d_ws, size_t ws_size,
                              hipStream_t stream) {
  (void)in_sizes; (void)n_in; (void)out_size; (void)ws_size;
  const float* x     = (const float*)d_in[0];
  const float* state = (const float*)d_in[1];
  const float* gleak = (const float*)d_in[2];
  const float* vleak = (const float*)d_in[3];
  const float* cm    = (const float*)d_in[4];
  const float* sigma = (const float*)d_in[5];
  const float* mu    = (const float*)d_in[6];
  const float* w     = (const float*)d_in[7];
  const float* erev  = (const float*)d_in[8];
  const float* ssig  = (const float*)d_in[9];
  const float* smu   = (const float*)d_in[10];
  const float* sw    = (const float*)d_in[11];
  const float* serev = (const float*)d_in[12];
  const float* in_w  = (const float*)d_in[13];
  const float* in_b  = (const float*)d_in[14];
  const float* out_w = (const float*)d_in[15];
  const float* out_b = (const float*)d_in[16];

  float* ws = (float*)d_ws;
  float4* fusedR = (float4*)(ws);                 // 1,048,576 floats
  float4* fusedS = (float4*)(ws + 1048576);       //   524,288
  float4* cmg    = (float4*)(ws + 1572864);       //     2,048
  float*  pnA    = ws + 1574912;                  //   524,288  [4][BN]
  float*  pdA    = ws + 2099200;                  //   524,288
  float*  pnB    = ws + 2623488;                  //   524,288
  float*  pdB    = ws + 3147776;                  //   524,288
  float*  snf    = ws + 3672064;                  //   262,144  [2][BN]
  float*  sdf    = ws + 3934208;                  //   262,144
  float*  vA     = ws + 4196352;                  //   131,072
  float*  vB     = ws + 4327424;                  //   131,072  (end 4,458,496 fl = 17.8 MB)

  prep_kernel<<<1536, 256, 0, stream>>>(sigma, mu, w, erev, ssig, smu, sw, serev,
                                        gleak, vleak, cm, fusedR, fusedS, cmg);
  sensory_kernel<<<256, 256, 0, stream>>>(x, in_w, in_b, fusedS, snf, sdf);

  // step 0: partials0(v0=state) -> A
  unfold_kernel<<<512, 256, 0, stream>>>(fusedR, state, pnA, pdA, snf, sdf, cmg,
                                         vA, pnA, pdA, 1);
  // step 1: v1=f(state,A) -> vA; partials1 -> B
  unfold_kernel<<<512, 256, 0, stream>>>(fusedR, state, pnA, pdA, snf, sdf, cmg,
                                         vA, pnB, pdB, 0);
  // step 2: v2=f(vA,B) -> vB; partials2 -> A
  unfold_kernel<<<512, 256, 0, stream>>>(fusedR, vA, pnB, pdB, snf, sdf, cmg,
                                         vB, pnA, pdA, 0);
  // step 3: v3=f(vB,A) -> vA; partials3 -> B
  unfold_kernel<<<512, 256, 0, stream>>>(fusedR, vB, pnA, pdA, snf, sdf, cmg,
                                         vA, pnB, pdB, 0);
  // step 4: v4=f(vA,B) -> vB; partials4 -> A
  unfold_kernel<<<512, 256, 0, stream>>>(fusedR, vA, pnB, pdB, snf, sdf, cmg,
                                         vB, pnA, pdA, 0);
  // step 5: v5=f(vB,A) -> vA; partials5 -> B
  unfold_kernel<<<512, 256, 0, stream>>>(fusedR, vB, pnA, pdA, snf, sdf, cmg,
                                         vA, pnB, pdB, 0);
  // final: v6=f(vA,B) -> out
  final_kernel<<<512, 256, 0, stream>>>(vA, pnB, pdB, snf, sdf, cmg,
                                        out_w, out_b, (float*)d_out);
}

// Round 2
// 158.184 us; speedup vs baseline: 1.2414x; 1.2414x over previous
//
#include <hip/hip_runtime.h>

#define UNITS 512
#define SENSD 256
#define BATCH 256
#define BN (BATCH * UNITS)
#define LOG2E 1.44269504088896340736f
#define CMF (6.0f / 1.001f)   // ODE_UNFOLDS / (ELAPSED_TIME + 0.001)

__device__ __forceinline__ float frcp(float x)  { return __builtin_amdgcn_rcpf(x); }
__device__ __forceinline__ float fexp2(float x) { return __builtin_amdgcn_exp2f(x); }

// Fused params: fusedR/fusedS[pq] = {-sigma*log2e, sigma*mu*log2e, w, w*erev}
// cmg[p] = {cm_t, gleak*vleak, cm_t+gleak+eps, 0}
__global__ __launch_bounds__(256) void prep_kernel(
    const float* __restrict__ sigma, const float* __restrict__ mu,
    const float* __restrict__ w, const float* __restrict__ erev,
    const float* __restrict__ ssig, const float* __restrict__ smu,
    const float* __restrict__ sw, const float* __restrict__ serev,
    const float* __restrict__ gleak, const float* __restrict__ vleak,
    const float* __restrict__ cm,
    float4* __restrict__ fusedR, float4* __restrict__ fusedS,
    float4* __restrict__ cmg) {
  int idx = blockIdx.x * 256 + threadIdx.x;
  if (idx < UNITS * UNITS) {
    float s = sigma[idx], m = mu[idx], ww = w[idx], e = erev[idx];
    fusedR[idx] = make_float4(-s * LOG2E, s * m * LOG2E, ww, ww * e);
  } else {
    int j = idx - UNITS * UNITS;
    if (j < SENSD * UNITS) {
      float s = ssig[j], m = smu[j], ww = sw[j], e = serev[j];
      fusedS[j] = make_float4(-s * LOG2E, s * m * LOG2E, ww, ww * e);
    }
  }
  if (idx < UNITS) {
    float cmt = cm[idx] * CMF, gl = gleak[idx];
    cmg[idx] = make_float4(cmt, gl * vleak[idx], cmt + gl + 1e-8f, 0.f);
  }
}

// Sensory partials over 2 d-chunks of 128 (round-0 proven structure).
// grid 512: bi = phs + 2*(qt + 8*bt); phs<2, qt<8 (q64), bt<32 (btile 8)
// 256 thr = 64 q-lanes x 4 bgroups x 2 rows. Plane-layout outputs snf/sdf[2][BN].
__global__ __launch_bounds__(256) void sensory_kernel(
    const float* __restrict__ x, const float* __restrict__ in_w, const float* __restrict__ in_b,
    const float4* __restrict__ fusedS,
    float* __restrict__ snf, float* __restrict__ sdf) {
  __shared__ float xl[8][128];
  int bi = blockIdx.x;
  int phs = bi & 1, qt = (bi >> 1) & 7, bt = bi >> 4;
  int tid = threadIdx.x;
  for (int i = tid; i < 1024; i += 256) {
    int br = i >> 7, dl = i & 127;
    int d = phs * 128 + dl;
    xl[br][dl] = fmaf(x[(bt * 8 + br) * SENSD + d], in_w[d], in_b[d]);
  }
  __syncthreads();
  int ql = tid & 63, bg = tid >> 6;
  int q = qt * 64 + ql;
  int r0 = bg * 2;
  const float4* F = fusedS + (size_t)(phs * 128) * UNITS + q;
  float n0 = 0.f, dn0 = 0.f, n1 = 0.f, dn1 = 0.f;
  #pragma unroll 8
  for (int dd = 0; dd < 128; ++dd) {
    float4 f = F[(size_t)dd * UNITS];
    float v0 = xl[r0][dd], v1 = xl[r0 + 1][dd];
    float t0 = fexp2(fmaf(f.x, v0, f.y));
    float t1 = fexp2(fmaf(f.x, v1, f.y));
    float s0 = frcp(1.0f + t0);
    float s1 = frcp(1.0f + t1);
    n0 = fmaf(f.w, s0, n0);  dn0 = fmaf(f.z, s0, dn0);
    n1 = fmaf(f.w, s1, n1);  dn1 = fmaf(f.z, s1, dn1);
  }
  int bp0 = (bt * 8 + r0) * UNITS + q;
  size_t o = (size_t)phs * BN + bp0;
  snf[o] = n0;         sdf[o] = dn0;
  snf[o + UNITS] = n1; sdf[o + UNITS] = dn1;
}

// One ODE unfold, 4 batch rows per thread, p-chunk 64.
// grid 1024 x 256 thr: bi = ph + 8*(qt + 8*bt); ph<8 (p-chunk 64), qt<8 (q64),
// bt<16 (btile 16). 4 blocks/CU => 16 waves/CU. Prologue reconstructs v_k for
// this (ph,bt) tile from plane partials [8][BN]; qt==0 blocks persist to vout.
__global__ __launch_bounds__(256, 4) void unfold_kernel(
    const float4* __restrict__ fusedR, const float* __restrict__ vprev,
    const float* __restrict__ pn_in, const float* __restrict__ pd_in,  // [8][BN]
    const float* __restrict__ snf, const float* __restrict__ sdf,      // [2][BN]
    const float4* __restrict__ cmg,
    float* __restrict__ vout,
    float* __restrict__ pn_out, float* __restrict__ pd_out,            // [8][BN]
    int first) {
  __shared__ float vl[64][20];   // [p-lane][batch-row], pad 20 -> 16B-aligned float4 rows
  int bi = blockIdx.x;
  int ph = bi & 7, qt = (bi >> 3) & 7, bt = bi >> 6;
  int tid = threadIdx.x;
  if (first) {
    for (int i = tid; i < 1024; i += 256) {
      int br = i >> 6, pl = i & 63;
      vl[pl][br] = vprev[(bt * 16 + br) * UNITS + ph * 64 + pl];
    }
  } else {
    for (int i = tid; i < 1024; i += 256) {
      int br = i >> 6, pl = i & 63;
      int p = ph * 64 + pl;
      int bp = (bt * 16 + br) * UNITS + p;
      float num = ((pn_in[bp] + pn_in[BN + bp]) + (pn_in[2 * BN + bp] + pn_in[3 * BN + bp]))
                + ((pn_in[4 * BN + bp] + pn_in[5 * BN + bp]) + (pn_in[6 * BN + bp] + pn_in[7 * BN + bp]))
                + (snf[bp] + snf[BN + bp]);
      float den = ((pd_in[bp] + pd_in[BN + bp]) + (pd_in[2 * BN + bp] + pd_in[3 * BN + bp]))
                + ((pd_in[4 * BN + bp] + pd_in[5 * BN + bp]) + (pd_in[6 * BN + bp] + pd_in[7 * BN + bp]))
                + (sdf[bp] + sdf[BN + bp]);
      float4 c = cmg[p];
      float v = fmaf(c.x, vprev[bp], c.y + num) * frcp(c.z + den);
      vl[pl][br] = v;
      if (qt == 0) vout[bp] = v;
    }
  }
  __syncthreads();
  int ql = tid & 63, bg = tid >> 6;   // bg < 4
  int q = qt * 64 + ql;
  int r0 = bg * 4;
  const float4* F = fusedR + (size_t)(ph * 64) * UNITS + q;
  float n0 = 0.f, n1 = 0.f, n2 = 0.f, n3 = 0.f;
  float d0 = 0.f, d1 = 0.f, d2 = 0.f, d3 = 0.f;
  #pragma unroll 8
  for (int pp = 0; pp < 64; ++pp) {
    float4 f = F[(size_t)pp * UNITS];
    float4 vv = *(const float4*)&vl[pp][r0];   // wave-broadcast ds_read_b128
    float t0 = fexp2(fmaf(f.x, vv.x, f.y));
    float t1 = fexp2(fmaf(f.x, vv.y, f.y));
    float t2 = fexp2(fmaf(f.x, vv.z, f.y));
    float t3 = fexp2(fmaf(f.x, vv.w, f.y));
    float s0 = frcp(1.0f + t0);
    float s1 = frcp(1.0f + t1);
    float s2 = frcp(1.0f + t2);
    float s3 = frcp(1.0f + t3);
    n0 = fmaf(f.w, s0, n0);  d0 = fmaf(f.z, s0, d0);
    n1 = fmaf(f.w, s1, n1);  d1 = fmaf(f.z, s1, d1);
    n2 = fmaf(f.w, s2, n2);  d2 = fmaf(f.z, s2, d2);
    n3 = fmaf(f.w, s3, n3);  d3 = fmaf(f.z, s3, d3);
  }
  int bp = (bt * 16 + r0) * UNITS + q;
  size_t o = (size_t)ph * BN + bp;
  pn_out[o] = n0;             pd_out[o] = d0;
  pn_out[o + UNITS] = n1;     pd_out[o + UNITS] = d1;
  pn_out[o + 2 * UNITS] = n2; pd_out[o + 2 * UNITS] = d2;
  pn_out[o + 3 * UNITS] = n3; pd_out[o + 3 * UNITS] = d3;
}

// Final combine: v6 from partials_5; write outputs and v_pre.
__global__ __launch_bounds__(256) void final_kernel(
    const float* __restrict__ vprev,
    const float* __restrict__ pn, const float* __restrict__ pd,   // [8][BN]
    const float* __restrict__ snf, const float* __restrict__ sdf, // [2][BN]
    const float4* __restrict__ cmg,
    const float* __restrict__ ow, const float* __restrict__ ob,
    float* __restrict__ out) {
  int idx = blockIdx.x * 256 + threadIdx.x;
  if (idx >= BN) return;
  int p = idx & (UNITS - 1);
  float num = ((pn[idx] + pn[BN + idx]) + (pn[2 * BN + idx] + pn[3 * BN + idx]))
            + ((pn[4 * BN + idx] + pn[5 * BN + idx]) + (pn[6 * BN + idx] + pn[7 * BN + idx]))
            + (snf[idx] + snf[BN + idx]);
  float den = ((pd[idx] + pd[BN + idx]) + (pd[2 * BN + idx] + pd[3 * BN + idx]))
            + ((pd[4 * BN + idx] + pd[5 * BN + idx]) + (pd[6 * BN + idx] + pd[7 * BN + idx]))
            + (sdf[idx] + sdf[BN + idx]);
  float4 c = cmg[p];
  float v = fmaf(c.x, vprev[idx], c.y + num) * frcp(c.z + den);
  out[idx] = fmaf(v, ow[p], ob[p]);
  out[BN + idx] = v;
}

extern "C" void kernel_launch(void* const* d_in, const int* in_sizes, int n_in,
                              void* d_out, int out_size, void* d_ws, size_t ws_size,
                              hipStream_t stream) {
  (void)in_sizes; (void)n_in; (void)out_size; (void)ws_size;
  const float* x     = (const float*)d_in[0];
  const float* state = (const float*)d_in[1];
  const float* gleak = (const float*)d_in[2];
  const float* vleak = (const float*)d_in[3];
  const float* cm    = (const float*)d_in[4];
  const float* sigma = (const float*)d_in[5];
  const float* mu    = (const float*)d_in[6];
  const float* w     = (const float*)d_in[7];
  const float* erev  = (const float*)d_in[8];
  const float* ssig  = (const float*)d_in[9];
  const float* smu   = (const float*)d_in[10];
  const float* sw    = (const float*)d_in[11];
  const float* serev = (const float*)d_in[12];
  const float* in_w  = (const float*)d_in[13];
  const float* in_b  = (const float*)d_in[14];
  const float* out_w = (const float*)d_in[15];
  const float* out_b = (const float*)d_in[16];

  float* ws = (float*)d_ws;
  float4* fusedR = (float4*)(ws);                 // 1,048,576 floats
  float4* fusedS = (float4*)(ws + 1048576);       //   524,288
  float4* cmg    = (float4*)(ws + 1572864);       //     2,048
  float*  pnA    = ws + 1574912;                  // 1,048,576  [8][BN]
  float*  pdA    = ws + 2623488;                  // 1,048,576
  float*  pnB    = ws + 3672064;                  // 1,048,576
  float*  pdB    = ws + 4720640;                  // 1,048,576
  float*  snf    = ws + 5769216;                  //   262,144  [2][BN]
  float*  sdf    = ws + 6031360;                  //   262,144
  float*  vA     = ws + 6293504;                  //   131,072
  float*  vB     = ws + 6424576;                  //   131,072  (end 6,555,648 fl = 26.2 MB)

  prep_kernel<<<1536, 256, 0, stream>>>(sigma, mu, w, erev, ssig, smu, sw, serev,
                                        gleak, vleak, cm, fusedR, fusedS, cmg);
  sensory_kernel<<<512, 256, 0, stream>>>(x, in_w, in_b, fusedS, snf, sdf);

  // step 0: partials0(v0=state) -> A
  unfold_kernel<<<1024, 256, 0, stream>>>(fusedR, state, pnA, pdA, snf, sdf, cmg,
                                          vA, pnA, pdA, 1);
  // step 1: v1=f(state,A) -> vA; partials1 -> B
  unfold_kernel<<<1024, 256, 0, stream>>>(fusedR, state, pnA, pdA, snf, sdf, cmg,
                                          vA, pnB, pdB, 0);
  // step 2: v2=f(vA,B) -> vB; partials2 -> A
  unfold_kernel<<<1024, 256, 0, stream>>>(fusedR, vA, pnB, pdB, snf, sdf, cmg,
                                          vB, pnA, pdA, 0);
  // step 3: v3=f(vB,A) -> vA; partials3 -> B
  unfold_kernel<<<1024, 256, 0, stream>>>(fusedR, vB, pnA, pdA, snf, sdf, cmg,
                                          vA, pnB, pdB, 0);
  // step 4: v4=f(vA,B) -> vB; partials4 -> A
  unfold_kernel<<<1024, 256, 0, stream>>>(fusedR, vA, pnB, pdB, snf, sdf, cmg,
                                          vB, pnA, pdA, 0);
  // step 5: v5=f(vB,A) -> vA; partials5 -> B
  unfold_kernel<<<1024, 256, 0, stream>>>(fusedR, vB, pnA, pdA, snf, sdf, cmg,
                                          vA, pnB, pdB, 0);
  // final: v6=f(vA,B) -> out
  final_kernel<<<512, 256, 0, stream>>>(vA, pnB, pdB, snf, sdf, cmg,
                                        out_w, out_b, (float*)d_out);
}

// Round 3
// 157.606 us; speedup vs baseline: 1.2460x; 1.0037x over previous
//
#include <hip/hip_runtime.h>

#define UNITS 512
#define SENSD 256
#define BATCH 256
#define BN (BATCH * UNITS)
#define LOG2E 1.44269504088896340736f
#define CMF (6.0f / 1.001f)   // ODE_UNFOLDS / (ELAPSED_TIME + 0.001)

__device__ __forceinline__ float frcp(float x)  { return __builtin_amdgcn_rcpf(x); }
__device__ __forceinline__ float fexp2(float x) { return __builtin_amdgcn_exp2f(x); }

// Fused params: fusedR/fusedS[pq] = {-sigma*log2e, sigma*mu*log2e, w, w*erev}
// cmg[p] = {cm_t, gleak*vleak, cm_t+gleak+eps, 0}
__global__ __launch_bounds__(256) void prep_kernel(
    const float* __restrict__ sigma, const float* __restrict__ mu,
    const float* __restrict__ w, const float* __restrict__ erev,
    const float* __restrict__ ssig, const float* __restrict__ smu,
    const float* __restrict__ sw, const float* __restrict__ serev,
    const float* __restrict__ gleak, const float* __restrict__ vleak,
    const float* __restrict__ cm,
    float4* __restrict__ fusedR, float4* __restrict__ fusedS,
    float4* __restrict__ cmg) {
  int idx = blockIdx.x * 256 + threadIdx.x;
  if (idx < UNITS * UNITS) {
    float s = sigma[idx], m = mu[idx], ww = w[idx], e = erev[idx];
    fusedR[idx] = make_float4(-s * LOG2E, s * m * LOG2E, ww, ww * e);
  } else {
    int j = idx - UNITS * UNITS;
    if (j < SENSD * UNITS) {
      float s = ssig[j], m = smu[j], ww = sw[j], e = serev[j];
      fusedS[j] = make_float4(-s * LOG2E, s * m * LOG2E, ww, ww * e);
    }
  }
  if (idx < UNITS) {
    float cmt = cm[idx] * CMF, gl = gleak[idx];
    cmg[idx] = make_float4(cmt, gl * vleak[idx], cmt + gl + 1e-8f, 0.f);
  }
}

// Sensory partials over 4 d-chunks of 64.
// grid 1024: bi = phs + 4*(qt + 8*bt); phs<4, qt<8 (q64), bt<32 (btile 8)
// 256 thr = 64 q-lanes x 4 bgroups x 2 rows. Plane outputs snf/sdf[4][BN].
// 4 blocks/CU -> 16 waves/CU.
__global__ __launch_bounds__(256, 4) void sensory_kernel(
    const float* __restrict__ x, const float* __restrict__ in_w, const float* __restrict__ in_b,
    const float4* __restrict__ fusedS,
    float* __restrict__ snf, float* __restrict__ sdf) {
  __shared__ float xl[8][64];
  int bi = blockIdx.x;
  int phs = bi & 3, qt = (bi >> 2) & 7, bt = bi >> 5;
  int tid = threadIdx.x;
  for (int i = tid; i < 512; i += 256) {
    int br = i >> 6, dl = i & 63;
    int d = phs * 64 + dl;
    xl[br][dl] = fmaf(x[(bt * 8 + br) * SENSD + d], in_w[d], in_b[d]);
  }
  __syncthreads();
  int ql = tid & 63, bg = tid >> 6;
  int q = qt * 64 + ql;
  int r0 = bg * 2;
  const float4* F = fusedS + (size_t)(phs * 64) * UNITS + q;
  float n0 = 0.f, dn0 = 0.f, n1 = 0.f, dn1 = 0.f;
  #pragma unroll 4
  for (int dd = 0; dd < 64; ++dd) {
    float4 f = F[(size_t)dd * UNITS];
    float v0 = xl[r0][dd], v1 = xl[r0 + 1][dd];
    float t0 = fexp2(fmaf(f.x, v0, f.y));
    float t1 = fexp2(fmaf(f.x, v1, f.y));
    float s0 = frcp(1.0f + t0);
    float s1 = frcp(1.0f + t1);
    n0 = fmaf(f.w, s0, n0);  dn0 = fmaf(f.z, s0, dn0);
    n1 = fmaf(f.w, s1, n1);  dn1 = fmaf(f.z, s1, dn1);
  }
  int bp0 = (bt * 8 + r0) * UNITS + q;
  size_t o = (size_t)phs * BN + bp0;
  snf[o] = n0;         sdf[o] = dn0;
  snf[o + UNITS] = n1; sdf[o + UNITS] = dn1;
}

// One ODE unfold, 4 batch rows per thread, p-chunk 32.
// grid 2048 x 256 thr: bi = ph + 16*(qt + 8*bt); ph<16 (p-chunk 32), qt<8 (q64),
// bt<16 (btile 16). 6 blocks/CU resident -> 24 waves/CU. Prologue reconstructs
// v_k for this (ph,bt) tile from plane partials [16][BN]; qt==0 persists to vout.
__global__ __launch_bounds__(256, 6) void unfold_kernel(
    const float4* __restrict__ fusedR, const float* __restrict__ vprev,
    const float* __restrict__ pn_in, const float* __restrict__ pd_in,  // [16][BN]
    const float* __restrict__ snf, const float* __restrict__ sdf,      // [4][BN]
    const float4* __restrict__ cmg,
    float* __restrict__ vout,
    float* __restrict__ pn_out, float* __restrict__ pd_out,            // [16][BN]
    int first) {
  __shared__ float vl[32][20];   // [p-lane][batch-row], pad 20 -> 16B-aligned float4 rows
  int bi = blockIdx.x;
  int ph = bi & 15, qt = (bi >> 4) & 7, bt = bi >> 7;
  int tid = threadIdx.x;
  if (first) {
    for (int i = tid; i < 512; i += 256) {
      int br = i >> 5, pl = i & 31;
      vl[pl][br] = vprev[(bt * 16 + br) * UNITS + ph * 32 + pl];
    }
  } else {
    for (int i = tid; i < 512; i += 256) {
      int br = i >> 5, pl = i & 31;
      int p = ph * 32 + pl;
      int bp = (bt * 16 + br) * UNITS + p;
      float num = 0.f, den = 0.f;
      #pragma unroll
      for (int k = 0; k < 16; ++k) {
        num += pn_in[k * BN + bp];
        den += pd_in[k * BN + bp];
      }
      #pragma unroll
      for (int k = 0; k < 4; ++k) {
        num += snf[k * BN + bp];
        den += sdf[k * BN + bp];
      }
      float4 c = cmg[p];
      float v = fmaf(c.x, vprev[bp], c.y + num) * frcp(c.z + den);
      vl[pl][br] = v;
      if (qt == 0) vout[bp] = v;
    }
  }
  __syncthreads();
  int ql = tid & 63, bg = tid >> 6;   // bg < 4
  int q = qt * 64 + ql;
  int r0 = bg * 4;
  const float4* F = fusedR + (size_t)(ph * 32) * UNITS + q;
  float n0 = 0.f, n1 = 0.f, n2 = 0.f, n3 = 0.f;
  float d0 = 0.f, d1 = 0.f, d2 = 0.f, d3 = 0.f;
  #pragma unroll 4
  for (int pp = 0; pp < 32; ++pp) {
    float4 f = F[(size_t)pp * UNITS];
    float4 vv = *(const float4*)&vl[pp][r0];   // wave-broadcast ds_read_b128
    float t0 = fexp2(fmaf(f.x, vv.x, f.y));
    float t1 = fexp2(fmaf(f.x, vv.y, f.y));
    float t2 = fexp2(fmaf(f.x, vv.z, f.y));
    float t3 = fexp2(fmaf(f.x, vv.w, f.y));
    float s0 = frcp(1.0f + t0);
    float s1 = frcp(1.0f + t1);
    float s2 = frcp(1.0f + t2);
    float s3 = frcp(1.0f + t3);
    n0 = fmaf(f.w, s0, n0);  d0 = fmaf(f.z, s0, d0);
    n1 = fmaf(f.w, s1, n1);  d1 = fmaf(f.z, s1, d1);
    n2 = fmaf(f.w, s2, n2);  d2 = fmaf(f.z, s2, d2);
    n3 = fmaf(f.w, s3, n3);  d3 = fmaf(f.z, s3, d3);
  }
  int bp = (bt * 16 + r0) * UNITS + q;
  size_t o = (size_t)ph * BN + bp;
  pn_out[o] = n0;             pd_out[o] = d0;
  pn_out[o + UNITS] = n1;     pd_out[o + UNITS] = d1;
  pn_out[o + 2 * UNITS] = n2; pd_out[o + 2 * UNITS] = d2;
  pn_out[o + 3 * UNITS] = n3; pd_out[o + 3 * UNITS] = d3;
}

// Final combine: v6 from partials_5; write outputs and v_pre.
__global__ __launch_bounds__(256) void final_kernel(
    const float* __restrict__ vprev,
    const float* __restrict__ pn, const float* __restrict__ pd,   // [16][BN]
    const float* __restrict__ snf, const float* __restrict__ sdf, // [4][BN]
    const float4* __restrict__ cmg,
    const float* __restrict__ ow, const float* __restrict__ ob,
    float* __restrict__ out) {
  int idx = blockIdx.x * 256 + threadIdx.x;
  if (idx >= BN) return;
  int p = idx & (UNITS - 1);
  float num = 0.f, den = 0.f;
  #pragma unroll
  for (int k = 0; k < 16; ++k) {
    num += pn[k * BN + idx];
    den += pd[k * BN + idx];
  }
  #pragma unroll
  for (int k = 0; k < 4; ++k) {
    num += snf[k * BN + idx];
    den += sdf[k * BN + idx];
  }
  float4 c = cmg[p];
  float v = fmaf(c.x, vprev[idx], c.y + num) * frcp(c.z + den);
  out[idx] = fmaf(v, ow[p], ob[p]);
  out[BN + idx] = v;
}

extern "C" void kernel_launch(void* const* d_in, const int* in_sizes, int n_in,
                              void* d_out, int out_size, void* d_ws, size_t ws_size,
                              hipStream_t stream) {
  (void)in_sizes; (void)n_in; (void)out_size; (void)ws_size;
  const float* x     = (const float*)d_in[0];
  const float* state = (const float*)d_in[1];
  const float* gleak = (const float*)d_in[2];
  const float* vleak = (const float*)d_in[3];
  const float* cm    = (const float*)d_in[4];
  const float* sigma = (const float*)d_in[5];
  const float* mu    = (const float*)d_in[6];
  const float* w     = (const float*)d_in[7];
  const float* erev  = (const float*)d_in[8];
  const float* ssig  = (const float*)d_in[9];
  const float* smu   = (const float*)d_in[10];
  const float* sw    = (const float*)d_in[11];
  const float* serev = (const float*)d_in[12];
  const float* in_w  = (const float*)d_in[13];
  const float* in_b  = (const float*)d_in[14];
  const float* out_w = (const float*)d_in[15];
  const float* out_b = (const float*)d_in[16];

  float* ws = (float*)d_ws;
  float4* fusedR = (float4*)(ws);                 // 1,048,576 floats
  float4* fusedS = (float4*)(ws + 1048576);       //   524,288
  float4* cmg    = (float4*)(ws + 1572864);       //     2,048
  float*  pnA    = ws + 1574912;                  // 2,097,152  [16][BN]
  float*  pdA    = ws + 3672064;                  // 2,097,152
  float*  pnB    = ws + 5769216;                  // 2,097,152
  float*  pdB    = ws + 7866368;                  // 2,097,152
  float*  snf    = ws + 9963520;                  //   524,288  [4][BN]
  float*  sdf    = ws + 10487808;                 //   524,288
  float*  vA     = ws + 11012096;                 //   131,072
  float*  vB     = ws + 11143168;                 //   131,072  (end 11,274,240 fl = 45.1 MB)

  prep_kernel<<<1536, 256, 0, stream>>>(sigma, mu, w, erev, ssig, smu, sw, serev,
                                        gleak, vleak, cm, fusedR, fusedS, cmg);
  sensory_kernel<<<1024, 256, 0, stream>>>(x, in_w, in_b, fusedS, snf, sdf);

  // step 0: partials0(v0=state) -> A
  unfold_kernel<<<2048, 256, 0, stream>>>(fusedR, state, pnA, pdA, snf, sdf, cmg,
                                          vA, pnA, pdA, 1);
  // step 1: v1=f(state,A) -> vA; partials1 -> B
  unfold_kernel<<<2048, 256, 0, stream>>>(fusedR, state, pnA, pdA, snf, sdf, cmg,
                                          vA, pnB, pdB, 0);
  // step 2: v2=f(vA,B) -> vB; partials2 -> A
  unfold_kernel<<<2048, 256, 0, stream>>>(fusedR, vA, pnB, pdB, snf, sdf, cmg,
                                          vB, pnA, pdA, 0);
  // step 3: v3=f(vB,A) -> vA; partials3 -> B
  unfold_kernel<<<2048, 256, 0, stream>>>(fusedR, vB, pnA, pdA, snf, sdf, cmg,
                                          vA, pnB, pdB, 0);
  // step 4: v4=f(vA,B) -> vB; partials4 -> A
  unfold_kernel<<<2048, 256, 0, stream>>>(fusedR, vA, pnB, pdB, snf, sdf, cmg,
                                          vB, pnA, pdA, 0);
  // step 5: v5=f(vB,A) -> vA; partials5 -> B
  unfold_kernel<<<2048, 256, 0, stream>>>(fusedR, vB, pnA, pdA, snf, sdf, cmg,
                                          vA, pnB, pdB, 0);
  // final: v6=f(vA,B) -> out
  final_kernel<<<512, 256, 0, stream>>>(vA, pnB, pdB, snf, sdf, cmg,
                                        out_w, out_b, (float*)d_out);
}